// Round 1
// 2863.782 us; speedup vs baseline: 1.0195x; 1.0195x over previous
//
#include <hip/hip_runtime.h>
#include <math.h>

constexpr int C_B = 2, C_S = 1024, C_D = 512, C_H = 8, C_DH = 64,
              C_F = 2048, C_L = 6, C_V = 32000;
constexpr float C_EPS = 1e-6f;

using bf16x8 = __attribute__((ext_vector_type(8))) __bf16;
using bf16x4v = __attribute__((ext_vector_type(4))) __bf16;
using f32x4  = __attribute__((ext_vector_type(4))) float;

__device__ __forceinline__ f32x4 mfma16(bf16x8 a, bf16x8 b, f32x4 c) {
  return __builtin_amdgcn_mfma_f32_16x16x32_bf16(a, b, c, 0, 0, 0);
}

__device__ __forceinline__ void async16(const __bf16* g, __bf16* l) {
  __builtin_amdgcn_global_load_lds(
      (const __attribute__((address_space(1))) void*)g,
      (__attribute__((address_space(3))) void*)l, 16, 0, 0);
}

__device__ __forceinline__ float block_sum(float v, float* sbuf) {
#pragma unroll
  for (int o = 32; o > 0; o >>= 1) v += __shfl_down(v, o);
  __syncthreads();
  if ((threadIdx.x & 63) == 0) sbuf[threadIdx.x >> 6] = v;
  __syncthreads();
  return (sbuf[0] + sbuf[1]) + (sbuf[2] + sbuf[3]);
}

__device__ __forceinline__ float block_max(float v, float* sbuf) {
#pragma unroll
  for (int o = 32; o > 0; o >>= 1) v = fmaxf(v, __shfl_down(v, o));
  __syncthreads();
  if ((threadIdx.x & 63) == 0) sbuf[threadIdx.x >> 6] = v;
  __syncthreads();
  return fmaxf(fmaxf(sbuf[0], sbuf[1]), fmaxf(sbuf[2], sbuf[3]));
}

// ---------------------------------------------------------------------------
// bf16 GEMM, B in [N][K] layout. C[M,N] = scale*(A@B^T) + bias, epilogues:
// EPI 0: store bf16; 1: store bf16+relu; 3: store f32; 4: f32 atomicAdd
// (residual, bias only when zb==0; z = K-split index via sAb/sBb k-offsets).
// TRI: bias segmented per 512 cols (b0/b1/b2). SWAP: m from blockIdx.x.
// global_load_lds staging (16B/lane), XOR granule swizzle in LDS.
// ---------------------------------------------------------------------------
template <int BM, int BN, int EPI, bool TRI, bool SWAP>
__global__ __launch_bounds__(256) void gemm_bt(
    const __bf16* __restrict__ A, int lda, long sAb, long sAh,
    const __bf16* __restrict__ B, int ldb, long sBb, long sBh,
    void* __restrict__ Cv, int ldc, long sCb, long sCh,
    const float* __restrict__ b0, const float* __restrict__ b1,
    const float* __restrict__ b2, int K, int hdim, float scale) {
  constexpr int BK = 32;
  __shared__ __bf16 As[BM][BK];
  __shared__ __bf16 Bs[BN][BK];
  const int z = blockIdx.z;
  const int zb = z / hdim, zh = z - zb * hdim;
  const __bf16* Ap = A + (long)zb * sAb + (long)zh * sAh;
  const __bf16* Bp = B + (long)zb * sBb + (long)zh * sBh;
  const int m0 = (SWAP ? blockIdx.x : blockIdx.y) * BM;
  const int n0 = (SWAP ? blockIdx.y : blockIdx.x) * BN;
  const int t = threadIdx.x, lane = t & 63, w = t >> 6;
  const int wr = w >> 1, wc = w & 1;
  constexpr int WM = BM / 2, WN = BN / 2, TM = WM / 16, TN = WN / 16;
  constexpr int AI = BM / 64, BI = BN / 64;
  const int srow = lane >> 2;       // row within 16-row staging group
  const int sg = lane & 3;          // LDS granule this lane fills
  const int fr = lane & 15, fq = lane >> 4;

  f32x4 acc[TM][TN] = {};
  for (int k0 = 0; k0 < K; k0 += BK) {
#pragma unroll
    for (int j = 0; j < AI; ++j) {
      const int r0 = w * (AI * 16) + j * 16;
      const int row = r0 + srow;
      const int s = sg ^ ((row >> 1) & 3);  // global k-seg for this granule
      async16(Ap + (long)(m0 + row) * lda + (k0 + s * 8), &As[r0][0]);
    }
#pragma unroll
    for (int j = 0; j < BI; ++j) {
      const int r0 = w * (BI * 16) + j * 16;
      const int row = r0 + srow;
      const int s = sg ^ ((row >> 1) & 3);
      async16(Bp + (long)(n0 + row) * ldb + (k0 + s * 8), &Bs[r0][0]);
    }
    __syncthreads();
    bf16x8 af[TM], bfr[TN];
#pragma unroll
    for (int i = 0; i < TM; ++i) {
      const int row = wr * WM + i * 16 + fr;
      const int g = fq ^ ((row >> 1) & 3);
      af[i] = *(const bf16x8*)&As[row][g * 8];
    }
#pragma unroll
    for (int i = 0; i < TN; ++i) {
      const int row = wc * WN + i * 16 + fr;
      const int g = fq ^ ((row >> 1) & 3);
      bfr[i] = *(const bf16x8*)&Bs[row][g * 8];
    }
#pragma unroll
    for (int i = 0; i < TM; ++i)
#pragma unroll
      for (int j = 0; j < TN; ++j) acc[i][j] = mfma16(af[i], bfr[j], acc[i][j]);
    __syncthreads();
  }

  const long co = (long)zb * sCb + (long)zh * sCh;
  const int rq = (lane >> 4) * 4;
#pragma unroll
  for (int i = 0; i < TM; ++i) {
#pragma unroll
    for (int j = 0; j < TN; ++j) {
      const int colg = n0 + wc * WN + j * 16 + fr;
      float bv = 0.f;
      if (b0) {
        if (TRI) {
          const float* bp = colg < 512 ? b0 : (colg < 1024 ? b1 : b2);
          bv = bp[colg & 511];
        } else {
          bv = b0[colg];
        }
      }
      if (EPI == 4 && zb != 0) bv = 0.f;
#pragma unroll
      for (int r = 0; r < 4; ++r) {
        const int rowg = m0 + wr * WM + i * 16 + rq + r;
        const long ci = co + (long)rowg * ldc + colg;
        float v = acc[i][j][r] * scale + bv;
        if (EPI == 0) ((__bf16*)Cv)[ci] = (__bf16)v;
        else if (EPI == 1) ((__bf16*)Cv)[ci] = (__bf16)fmaxf(v, 0.f);
        else if (EPI == 3) ((float*)Cv)[ci] = v;
        else atomicAdd((float*)Cv + ci, v);
      }
    }
  }
}

// ---------------------------------------------------------------------------
// transpose + f32->bf16: in [z][R][C] f32 -> out [z][C][R] bf16 (+outOff)
// ---------------------------------------------------------------------------
__global__ __launch_bounds__(256) void transpose_cvt(
    const float* __restrict__ in, __bf16* __restrict__ out, int R, int C,
    long inS, long outS, long outOff) {
  __shared__ __bf16 tile[32][33];
  in += (long)blockIdx.z * inS;
  out += (long)blockIdx.z * outS + outOff;
  const int c0 = blockIdx.x * 32, r0 = blockIdx.y * 32;
  const int tc = threadIdx.x & 31, tr = threadIdx.x >> 5;  // 8 rows/pass
#pragma unroll
  for (int j = 0; j < 32; j += 8)
    tile[tr + j][tc] = (__bf16)in[(long)(r0 + tr + j) * C + (c0 + tc)];
  __syncthreads();
#pragma unroll
  for (int j = 0; j < 32; j += 8)
    out[(long)(c0 + tr + j) * R + (r0 + tc)] = tile[tc][tr + j];
}

// ---------------------------------------------------------------------------
// V transpose: qkv[b*S+s][1024 + h*64 + dh] -> vT[(b*8+h)*64 + dh][s]
// ---------------------------------------------------------------------------
__global__ __launch_bounds__(256) void vtrans_kernel(
    const __bf16* __restrict__ qkv, __bf16* __restrict__ vT) {
  __shared__ __bf16 tile[32][33];
  const int z = blockIdx.z, b = z >> 3, h = z & 7;
  const int s0 = blockIdx.x * 32, d0 = blockIdx.y * 32;
  const int tc = threadIdx.x & 31, tr = threadIdx.x >> 5;
  const __bf16* src = qkv + (long)(b << 10) * 1536 + 1024 + h * 64;
#pragma unroll
  for (int j = 0; j < 32; j += 8)
    tile[tr + j][tc] = src[(long)(s0 + tr + j) * 1536 + (d0 + tc)];
  __syncthreads();
  __bf16* dst = vT + (long)z * 64 * 1024;
#pragma unroll
  for (int j = 0; j < 32; j += 8)
    dst[(long)(d0 + tr + j) * 1024 + (s0 + tc)] = tile[tc][tr + j];
}

// ---------------------------------------------------------------------------
__global__ __launch_bounds__(256) void embed_kernel(
    const int* __restrict__ tok, const float* __restrict__ emb,
    float* __restrict__ out) {
  const int bs = blockIdx.x;
  const int spos = bs & (C_S - 1);
  const int tk = tok[bs];
  const float* ep = emb + (long)tk * C_D;
  float* op = out + (long)bs * C_D;
  for (int d = threadIdx.x; d < C_D; d += 256) {
    const int i2 = d & ~1;
    const float freq = __expf((float)i2 * (-9.210340371976184f / 512.0f));
    const float ang = (float)spos * freq;
    const float pe = (d & 1) ? cosf(ang) : sinf(ang);
    op[d] = ep[d] * 22.62741699796952f + pe;
  }
}

__global__ __launch_bounds__(256) void ln_kernel(const float* __restrict__ x,
                                                 __bf16* __restrict__ out) {
  __shared__ float sbuf[4];
  const long row = blockIdx.x;
  const float* xp = x + row * C_D;
  __bf16* op = out + row * C_D;
  const int t = threadIdx.x;
  const float v0 = xp[t];
  const float v1 = xp[t + 256];
  const float mean = block_sum(v0 + v1, sbuf) * (1.0f / 512.0f);
  const float d0 = v0 - mean, d1 = v1 - mean;
  const float ss = block_sum(d0 * d0 + d1 * d1, sbuf);
  const float stdv = sqrtf(ss * (1.0f / 511.0f));
  const float inv = 1.0f / (stdv + C_EPS);
  op[t] = (__bf16)(d0 * inv);
  op[t + 256] = (__bf16)(d1 * inv);
}

// masked softmax over bf16 rows of length S=1024 (in-place)
template <int MODE>
__global__ __launch_bounds__(256) void softmax_kernel(
    __bf16* __restrict__ sc, const int* __restrict__ mask) {
  __shared__ float sbuf[4];
  const int row = blockIdx.x;  // (b*H+h)*S + q
  const int b = row >> 13;
  const int qpos = row & (C_S - 1);
  __bf16* p = sc + (long)row * C_S;
  const int t = threadIdx.x;
  const bf16x4v pv = *(const bf16x4v*)(p + t * 4);
  const int4 mk = (MODE == 0)
      ? *(const int4*)(mask + b * C_S + t * 4)
      : *(const int4*)(mask + ((long)b * C_S + qpos) * C_S + t * 4);
  float v[4];
  v[0] = mk.x == 0 ? -1e9f : (float)pv[0];
  v[1] = mk.y == 0 ? -1e9f : (float)pv[1];
  v[2] = mk.z == 0 ? -1e9f : (float)pv[2];
  v[3] = mk.w == 0 ? -1e9f : (float)pv[3];
  float mx = fmaxf(fmaxf(v[0], v[1]), fmaxf(v[2], v[3]));
  mx = block_max(mx, sbuf);
  float e[4], s = 0.f;
#pragma unroll
  for (int j = 0; j < 4; ++j) { e[j] = __expf(v[j] - mx); s += e[j]; }
  s = block_sum(s, sbuf);
  const float inv = 1.0f / s;
  bf16x4v o;
#pragma unroll
  for (int j = 0; j < 4; ++j) o[j] = (__bf16)(e[j] * inv);
  *(bf16x4v*)(p + t * 4) = o;
}

// ---------------------------------------------------------------------------
// log_softmax over rows of V=32000 f32, in-place.
// float4 loads (16B/lane), dual online (m,l) states to break the serial
// exp-dependence chain, fully unrolled so loads batch under one vmcnt window.
// Row = 31 float4 iters (31744 elems) + 256-elem scalar tail.
// ---------------------------------------------------------------------------
__global__ __launch_bounds__(256) void logsoftmax_kernel(float* __restrict__ out) {
  __shared__ float sm[4], sl[4];
  const long row = blockIdx.x;
  float* p = out + row * C_V;
  const int t = threadIdx.x, lane = t & 63, w = t >> 6;
  float m0 = -1e30f, l0 = 0.f, m1 = -1e30f, l1 = 0.f;
#pragma unroll
  for (int i = 0; i < 30; i += 2) {
    const f32x4 a = *(const f32x4*)(p + (long)i * 1024 + t * 4);
    const f32x4 b = *(const f32x4*)(p + (long)(i + 1) * 1024 + t * 4);
    {
      const float mx = fmaxf(fmaxf(a[0], a[1]), fmaxf(a[2], a[3]));
      const float mn = fmaxf(m0, mx);
      l0 = l0 * __expf(m0 - mn) +
           ((__expf(a[0] - mn) + __expf(a[1] - mn)) +
            (__expf(a[2] - mn) + __expf(a[3] - mn)));
      m0 = mn;
    }
    {
      const float mx = fmaxf(fmaxf(b[0], b[1]), fmaxf(b[2], b[3]));
      const float mn = fmaxf(m1, mx);
      l1 = l1 * __expf(m1 - mn) +
           ((__expf(b[0] - mn) + __expf(b[1] - mn)) +
            (__expf(b[2] - mn) + __expf(b[3] - mn)));
      m1 = mn;
    }
  }
  {  // vector iter 30
    const f32x4 a = *(const f32x4*)(p + (long)30 * 1024 + t * 4);
    const float mx = fmaxf(fmaxf(a[0], a[1]), fmaxf(a[2], a[3]));
    const float mn = fmaxf(m0, mx);
    l0 = l0 * __expf(m0 - mn) +
         ((__expf(a[0] - mn) + __expf(a[1] - mn)) +
          (__expf(a[2] - mn) + __expf(a[3] - mn)));
    m0 = mn;
  }
  {  // scalar tail: elements 31744..31999
    const float v = p[31744 + t];
    const float mn = fmaxf(m1, v);
    l1 = l1 * __expf(m1 - mn) + __expf(v - mn);
    m1 = mn;
  }
  // merge dual states
  float m = fmaxf(m0, m1);
  float l = l0 * __expf(m0 - m) + l1 * __expf(m1 - m);
#pragma unroll
  for (int o = 32; o > 0; o >>= 1) {
    const float m2 = __shfl_down(m, o), l2 = __shfl_down(l, o);
    const float M = fmaxf(m, m2);
    l = l * __expf(m - M) + l2 * __expf(m2 - M);
    m = M;
  }
  if (lane == 0) { sm[w] = m; sl[w] = l; }
  __syncthreads();
  const float M = fmaxf(fmaxf(sm[0], sm[1]), fmaxf(sm[2], sm[3]));
  const float L = sl[0] * __expf(sm[0] - M) + sl[1] * __expf(sm[1] - M) +
                  sl[2] * __expf(sm[2] - M) + sl[3] * __expf(sm[3] - M);
  const float lz = M + logf(L);
#pragma unroll
  for (int i = 0; i < 31; ++i) {
    f32x4 v = *(const f32x4*)(p + (long)i * 1024 + t * 4);
    v[0] -= lz; v[1] -= lz; v[2] -= lz; v[3] -= lz;
    *(f32x4*)(p + (long)i * 1024 + t * 4) = v;
  }
  p[31744 + t] -= lz;
}

// ---------------------------------------------------------------------------
extern "C" void kernel_launch(void* const* d_in, const int* in_sizes, int n_in,
                              void* d_out, int out_size, void* d_ws,
                              size_t ws_size, hipStream_t stream) {
  (void)in_sizes; (void)n_in; (void)out_size; (void)ws_size;
  const int* src = (const int*)d_in[0];
  const int* tgt = (const int*)d_in[1];
  const int* src_mask = (const int*)d_in[2];
  const int* tgt_mask = (const int*)d_in[3];
  const float* src_emb = (const float*)d_in[4];
  const float* tgt_emb = (const float*)d_in[5];
  const float* in_f[40];
  for (int i = 0; i < 40; ++i) in_f[i] = (const float*)d_in[i];
  float* out = (float*)d_out;

  // ---- workspace carve-up ----
  char* wp = (char*)d_ws;
  auto alloc = [&](size_t bytes) -> char* {
    char* r = wp; wp += (bytes + 255) & ~(size_t)255; return r;
  };
  const long eQKV = (long)6 * 1536 * 512, eDD = (long)6 * 512 * 512,
             eDF = (long)6 * 2048 * 512;
  __bf16* encQKV = (__bf16*)alloc(eQKV * 2);
  __bf16* dsaQKV = (__bf16*)alloc(eQKV * 2);
  __bf16* dcaQKV = (__bf16*)alloc(eQKV * 2);
  __bf16* encWoT = (__bf16*)alloc(eDD * 2);
  __bf16* dsaWoT = (__bf16*)alloc(eDD * 2);
  __bf16* dcaWoT = (__bf16*)alloc(eDD * 2);
  __bf16* encW1T = (__bf16*)alloc(eDF * 2);
  __bf16* encW2T = (__bf16*)alloc(eDF * 2);
  __bf16* decW1T = (__bf16*)alloc(eDF * 2);
  __bf16* decW2T = (__bf16*)alloc(eDF * 2);
  __bf16* projT  = (__bf16*)alloc((long)32000 * 512 * 2);
  float*  x      = (float*)alloc((long)2048 * 512 * 4);
  __bf16* h      = (__bf16*)alloc((long)2048 * 512 * 2);
  __bf16* encb   = (__bf16*)alloc((long)2048 * 512 * 2);
  __bf16* qkv    = (__bf16*)alloc((long)2048 * 1536 * 2);
  __bf16* vT     = (__bf16*)alloc((long)16 * 64 * 1024 * 2);
  __bf16* ob     = (__bf16*)alloc((long)2048 * 512 * 2);
  __bf16* mid    = (__bf16*)alloc((long)2048 * 2048 * 2);
  __bf16* scores = (__bf16*)alloc((long)16 * 1024 * 1024 * 2);

  auto tconv = [&](const float* in, __bf16* o, int R, int C, int Lz,
                   long outS, long outOff) {
    transpose_cvt<<<dim3(C / 32, R / 32, Lz), 256, 0, stream>>>(
        in, o, R, C, (long)R * C, outS, outOff);
  };
  // ---- weight conversion/transpose (per launch; ws is re-poisoned) ----
  tconv(in_f[6],  encQKV, 512, 512, 6, 1536 * 512, 0);
  tconv(in_f[8],  encQKV, 512, 512, 6, 1536 * 512, 512 * 512);
  tconv(in_f[10], encQKV, 512, 512, 6, 1536 * 512, 1024 * 512);
  tconv(in_f[12], encWoT, 512, 512, 6, 512 * 512, 0);
  tconv(in_f[14], encW1T, 512, 2048, 6, (long)2048 * 512, 0);
  tconv(in_f[16], encW2T, 2048, 512, 6, (long)2048 * 512, 0);
  tconv(in_f[18], dsaQKV, 512, 512, 6, 1536 * 512, 0);
  tconv(in_f[20], dsaQKV, 512, 512, 6, 1536 * 512, 512 * 512);
  tconv(in_f[22], dsaQKV, 512, 512, 6, 1536 * 512, 1024 * 512);
  tconv(in_f[24], dsaWoT, 512, 512, 6, 512 * 512, 0);
  tconv(in_f[26], dcaQKV, 512, 512, 6, 1536 * 512, 0);
  tconv(in_f[28], dcaQKV, 512, 512, 6, 1536 * 512, 512 * 512);
  tconv(in_f[30], dcaQKV, 512, 512, 6, 1536 * 512, 1024 * 512);
  tconv(in_f[32], dcaWoT, 512, 512, 6, 512 * 512, 0);
  tconv(in_f[34], decW1T, 512, 2048, 6, (long)2048 * 512, 0);
  tconv(in_f[36], decW2T, 2048, 512, 6, (long)2048 * 512, 0);
  tconv(in_f[38], projT, 512, 32000, 1, 0, 0);

  const long sAh64 = 64, sZA = (long)1024 * 1536, sZS = (long)1024 * 1024;

  auto attn_core = [&](const int* mask, int mode, const __bf16* woT_l,
                       const float* bo_l) {
    vtrans_kernel<<<dim3(32, 2, 16), 256, 0, stream>>>(qkv, vT);
    // scores = Q K^T / 8
    gemm_bt<128, 128, 0, false, false><<<dim3(8, 8, 16), 256, 0, stream>>>(
        qkv, 1536, sZA, sAh64, qkv + 512, 1536, sZA, sAh64, scores, 1024,
        (long)8 * sZS, sZS, nullptr, nullptr, nullptr, 64, 8, 0.125f);
    if (mode == 0)
      softmax_kernel<0><<<16384, 256, 0, stream>>>(scores, mask);
    else
      softmax_kernel<1><<<16384, 256, 0, stream>>>(scores, mask);
    // O = P V   (B = vT [dh][s])
    gemm_bt<64, 64, 0, false, false><<<dim3(1, 16, 16), 256, 0, stream>>>(
        scores, 1024, (long)8 * sZS, sZS, vT, 1024, (long)8 * 64 * 1024,
        (long)64 * 1024, ob, 512, (long)1024 * 512, 64, nullptr, nullptr,
        nullptr, 1024, 8, 1.f);
    // x += O Wo + bo   (split-K 2, atomic)
    gemm_bt<64, 64, 4, false, false><<<dim3(8, 32, 2), 256, 0, stream>>>(
        ob, 512, 256, 0, woT_l, 512, 256, 0, x, 512, 0, 0, bo_l, nullptr,
        nullptr, 256, 1, 1.f);
  };

  auto ffn = [&](const __bf16* w1T_l, const float* b1_l, const __bf16* w2T_l,
                 const float* b2_l) {
    gemm_bt<128, 64, 1, false, false><<<dim3(32, 16, 1), 256, 0, stream>>>(
        h, 512, 0, 0, w1T_l, 512, 0, 0, mid, 2048, 0, 0, b1_l, nullptr,
        nullptr, 512, 1, 1.f);
    gemm_bt<64, 64, 4, false, false><<<dim3(8, 32, 2), 256, 0, stream>>>(
        mid, 2048, 1024, 0, w2T_l, 2048, 1024, 0, x, 512, 0, 0, b2_l, nullptr,
        nullptr, 1024, 1, 1.f);
  };

  const int rows = C_B * C_S;

  // ================= encoder =================
  embed_kernel<<<rows, 256, 0, stream>>>(src, src_emb, x);
  for (int i = 0; i < C_L; ++i) {
    const long oW = (long)i * 1536 * 512, oB = (long)i * 512;
    ln_kernel<<<rows, 256, 0, stream>>>(x, h);
    gemm_bt<128, 64, 0, true, false><<<dim3(24, 16, 1), 256, 0, stream>>>(
        h, 512, 0, 0, encQKV + oW, 512, 0, 0, qkv, 1536, 0, 0,
        in_f[7] + oB, in_f[9] + oB, in_f[11] + oB, 512, 1, 1.f);
    attn_core(src_mask, 0, encWoT + (long)i * 512 * 512, in_f[13] + oB);
    ln_kernel<<<rows, 256, 0, stream>>>(x, h);
    ffn(encW1T + (long)i * 2048 * 512, in_f[15] + (long)i * 2048,
        encW2T + (long)i * 2048 * 512, in_f[17] + oB);
  }
  ln_kernel<<<rows, 256, 0, stream>>>(x, encb);

  // ================= decoder =================
  embed_kernel<<<rows, 256, 0, stream>>>(tgt, tgt_emb, x);
  for (int i = 0; i < C_L; ++i) {
    const long oW = (long)i * 1536 * 512, oB = (long)i * 512;
    // self-attn (reference quirk: src_mask)
    ln_kernel<<<rows, 256, 0, stream>>>(x, h);
    gemm_bt<128, 64, 0, true, false><<<dim3(24, 16, 1), 256, 0, stream>>>(
        h, 512, 0, 0, dsaQKV + oW, 512, 0, 0, qkv, 1536, 0, 0,
        in_f[19] + oB, in_f[21] + oB, in_f[23] + oB, 512, 1, 1.f);
    attn_core(src_mask, 0, dsaWoT + (long)i * 512 * 512, in_f[25] + oB);
    // cross-attn (reference quirk: tgt_mask); Q from h, K/V from encb
    ln_kernel<<<rows, 256, 0, stream>>>(x, h);
    gemm_bt<64, 64, 0, false, false><<<dim3(8, 32, 1), 256, 0, stream>>>(
        h, 512, 0, 0, dcaQKV + oW, 512, 0, 0, qkv, 1536, 0, 0,
        in_f[27] + oB, nullptr, nullptr, 512, 1, 1.f);
    gemm_bt<128, 64, 0, true, false><<<dim3(16, 16, 1), 256, 0, stream>>>(
        encb, 512, 0, 0, dcaQKV + oW + (long)512 * 512, 512, 0, 0, qkv + 512,
        1536, 0, 0, in_f[29] + oB, in_f[31] + oB, nullptr, 512, 1, 1.f);
    attn_core(tgt_mask, 1, dcaWoT + (long)i * 512 * 512, in_f[33] + oB);
    ln_kernel<<<rows, 256, 0, stream>>>(x, h);
    ffn(decW1T + (long)i * 2048 * 512, in_f[35] + (long)i * 2048,
        decW2T + (long)i * 2048 * 512, in_f[37] + oB);
  }
  ln_kernel<<<rows, 256, 0, stream>>>(x, h);

  // ---- final projection (SWAP grid: M-major for proj_w L2 reuse) ----
  gemm_bt<128, 128, 3, false, true><<<dim3(16, 250, 1), 256, 0, stream>>>(
      h, 512, 0, 0, projT, 512, 0, 0, out, 32000, 0, 0, in_f[39], nullptr,
      nullptr, 512, 1, 1.f);
  logsoftmax_kernel<<<rows, 256, 0, stream>>>(out);
}